// Round 7
// baseline (1486.466 us; speedup 1.0000x reference)
//
#include <hip/hip_runtime.h>
#include <hip/hip_bf16.h>

#define DEPTH 64
#define NH 8
#define SEQL 512
#define BATCH 4
#define FFDIM 128
#define PROJ (DEPTH*NH)   // 512
#define LOG2E 1.44269504088896340736f

// ---- DIAGNOSTIC ROUND: each kernel repeats its identical work REP times ----
// (memory clobber between reps forces real re-execution; outputs identical
// every rep => deterministic). Purpose: push each kernel's dispatch above the
// ~150us harness-fill floor so it claims a top-5 rocprof row with its own
// dur_us / hbm_gbps / FETCH_SIZE / MfmaUtil / OccupancyPercent.
#define REP_QKV  32
#define REP_PB   4
#define REP_ATTN 16
#define REP_TAIL 32

typedef __hip_bfloat16 bf16;
typedef __attribute__((ext_vector_type(8))) short short8;
typedef __attribute__((ext_vector_type(4))) float floatx4;

__device__ __forceinline__ short f2bs(float f) {
    __hip_bfloat16 h = __float2bfloat16(f);
    return *reinterpret_cast<short*>(&h);
}
__device__ __forceinline__ float bs2f(short s) {
    __hip_bfloat16 h = *reinterpret_cast<__hip_bfloat16*>(&s);
    return __bfloat162float(h);
}

// ---------------- K1: QKV projection via MFMA, fp32 -> bf16 ----------------
__global__ __launch_bounds__(256) void qkv_kernel(
    const float* __restrict__ seq, const float* __restrict__ Wq,
    const float* __restrict__ Wk, const float* __restrict__ Wv,
    bf16* __restrict__ q, bf16* __restrict__ k, bf16* __restrict__ vT)
{
    __shared__ __align__(16) short sS[64][72];
    __shared__ __align__(16) short sW[128][72];
    __shared__ __align__(16) short sT[128][72];
    int t = threadIdx.x;
    int lane = t & 63, w = t >> 6;
    const float* W; int vflag = 0;
    bf16* out;
    if (blockIdx.z == 0)      { W = Wq; out = q; }
    else if (blockIdx.z == 1) { W = Wk; out = k; }
    else                      { W = Wv; out = vT; vflag = 1; }
    int m0 = blockIdx.x * 64;
    int n0 = blockIdx.y * 128;
    int ln = lane & 15, g4 = lane >> 4;
    int mt = w;

    #pragma unroll 1
    for (int rep = 0; rep < REP_QKV; ++rep) {
        __syncthreads();
        for (int idx = t; idx < 4096; idx += 256) {
            int r = idx >> 6, kk = idx & 63;
            sS[r][kk] = f2bs(seq[(long)(m0 + r)*64 + kk]);
        }
        for (int idx = t; idx < 8192; idx += 256) {
            int kk = idx >> 7, n = idx & 127;
            sW[n][kk] = f2bs(W[kk*512 + n0 + n]);
        }
        __syncthreads();

        floatx4 acc[2][4];
        #pragma unroll
        for (int nh = 0; nh < 2; nh++)
            #pragma unroll
            for (int nt = 0; nt < 4; nt++) acc[nh][nt] = (floatx4){0.f,0.f,0.f,0.f};
        #pragma unroll
        for (int ks = 0; ks < 2; ks++) {
            short8 af = *(const short8*)&sS[mt*16 + ln][ks*32 + g4*8];
            #pragma unroll
            for (int nh = 0; nh < 2; nh++)
                #pragma unroll
                for (int nt = 0; nt < 4; nt++) {
                    short8 bfv = *(const short8*)&sW[nh*64 + nt*16 + ln][ks*32 + g4*8];
                    acc[nh][nt] = __builtin_amdgcn_mfma_f32_16x16x32_bf16(af, bfv, acc[nh][nt], 0, 0, 0);
                }
        }

        if (!vflag) {
            #pragma unroll
            for (int nh = 0; nh < 2; nh++)
                #pragma unroll
                for (int nt = 0; nt < 4; nt++)
                    #pragma unroll
                    for (int r = 0; r < 4; r++) {
                        int grow = m0 + mt*16 + g4*4 + r;
                        int col  = n0 + nh*64 + nt*16 + ln;
                        int b = grow >> 9, s = grow & 511;
                        int h = col >> 6, d = col & 63;
                        out[(((long)(b*8 + h)*512) + s)*64 + d] = __float2bfloat16(acc[nh][nt][r]);
                    }
        } else {
            __syncthreads();
            #pragma unroll
            for (int nh = 0; nh < 2; nh++)
                #pragma unroll
                for (int nt = 0; nt < 4; nt++)
                    #pragma unroll
                    for (int r = 0; r < 4; r++)
                        sT[nh*64 + nt*16 + ln][mt*16 + g4*4 + r] = f2bs(acc[nh][nt][r]);
            __syncthreads();
            int b = m0 >> 9, s0 = m0 & 511;
            for (int idx = t; idx < 1024; idx += 256) {
                int lc = idx >> 3, c8 = idx & 7;
                *(uint4*)(out + ((long)(b*512 + n0 + lc))*512 + s0 + c8*8) =
                    *(const uint4*)&sT[lc][c8*8];
            }
        }
        asm volatile("" ::: "memory");
    }
}

// ---------------- K2: positional bias (R5 structure), repeated ----------------
__global__ __launch_bounds__(256, 8) void pbias_kernel(
    const float* __restrict__ pos, const float* __restrict__ Wp,
    const float* __restrict__ bp, bf16* __restrict__ p)
{
    __shared__ __align__(16) float sW2[4][132];
    __shared__ float sb[8];
    int t = threadIdx.x;
    for (int i = t; i < 512; i += 256) {
        int sub = i >> 7, rest = i & 127;
        int lk = rest >> 3, h = rest & 7;
        int kk = ((lk >> 2) << 4) + sub*4 + (lk & 3);
        sW2[sub][lk*8 + h] = Wp[kk*8 + h];
    }
    if (t < 8) sb[t] = bp[t];
    __syncthreads();

    int sub = t & 3;
    int lr = t >> 2;
    long rowA = (long)blockIdx.x*128 + lr;
    long rowB = rowA + 64;

    #pragma unroll 1
    for (int rep = 0; rep < REP_PB; ++rep) {
        const float4* srcA = (const float4*)(pos + rowA*64);
        const float4* srcB = (const float4*)(pos + rowB*64);
        float4 chA[4], chB[4];
        #pragma unroll
        for (int i = 0; i < 4; i++) chA[i] = srcA[i*4 + sub];
        #pragma unroll
        for (int i = 0; i < 4; i++) chB[i] = srcB[i*4 + sub];

        float accA[8], accB[8];
        #pragma unroll
        for (int h = 0; h < 8; h++) { accA[h] = 0.f; accB[h] = 0.f; }
        #pragma unroll
        for (int i = 0; i < 4; i++) {
            #pragma unroll
            for (int e = 0; e < 4; e++) {
                int lk = i*4 + e;
                const float4* wr = (const float4*)&sW2[sub][lk*8];
                float4 wa = wr[0], wb = wr[1];
                float xA = ((const float*)&chA[i])[e];
                float xB = ((const float*)&chB[i])[e];
                accA[0] += xA*wa.x; accA[1] += xA*wa.y; accA[2] += xA*wa.z; accA[3] += xA*wa.w;
                accA[4] += xA*wb.x; accA[5] += xA*wb.y; accA[6] += xA*wb.z; accA[7] += xA*wb.w;
                accB[0] += xB*wa.x; accB[1] += xB*wa.y; accB[2] += xB*wa.z; accB[3] += xB*wa.w;
                accB[4] += xB*wb.x; accB[5] += xB*wb.y; accB[6] += xB*wb.z; accB[7] += xB*wb.w;
            }
        }
        #pragma unroll
        for (int h = 0; h < 8; h++) {
            accA[h] += __shfl_xor(accA[h], 1, 64);
            accA[h] += __shfl_xor(accA[h], 2, 64);
            accB[h] += __shfl_xor(accB[h], 1, 64);
            accB[h] += __shfl_xor(accB[h], 2, 64);
        }
        if (sub == 0) {
            short8 vA, vB;
            #pragma unroll
            for (int h = 0; h < 8; h++) {
                vA[h] = f2bs(accA[h] + sb[h]);
                vB[h] = f2bs(accB[h] + sb[h]);
            }
            *(short8*)(p + rowA*8) = vA;
            *(short8*)(p + rowB*8) = vB;
        }
        asm volatile("" ::: "memory");
    }
}

// ---------------- K3: flash attention (R5 structure), repeated ----------------
__global__ __launch_bounds__(256) void attn_kernel(
    const bf16* __restrict__ q, const bf16* __restrict__ k,
    const bf16* __restrict__ vT, const bf16* __restrict__ p,
    bf16* __restrict__ heads)
{
    __shared__ __align__(16) short sQ[64*72];
    __shared__ __align__(16) short sK[64*72];
    __shared__ __align__(16) short sV[64*72];
    __shared__ __align__(16) short sP[4][16*72];

    int t = threadIdx.x;
    int lane = t & 63, w = t >> 6;
    int bid = blockIdx.x;
    int it = bid & 7;
    int bh = bid >> 3;
    int i0 = it*64;
    int b = bh >> 3, h = bh & 7;

    const bf16* qb = q + ((long)bh*SEQL + i0)*DEPTH;
    const bf16* kb = k + (long)bh*SEQL*DEPTH;
    const bf16* vb = vT + (long)bh*DEPTH*SEQL;
    const bf16* pb = p + (((long)b*512 + i0)*512)*8 + h;
    int ln = lane & 15, g4 = lane >> 4;

    #pragma unroll 1
    for (int rep = 0; rep < REP_ATTN; ++rep) {
        __syncthreads();
        for (int c = t; c < 512; c += 256) {
            int r = c >> 3, c8 = c & 7;
            *(uint4*)((char*)sQ + r*144 + c8*16) = *(const uint4*)(qb + r*64 + c8*8);
        }

        float lsum[4];
        floatx4 oacc[4];
        #pragma unroll
        for (int r = 0; r < 4; r++) lsum[r] = 0.f;
        #pragma unroll
        for (int ds = 0; ds < 4; ds++) oacc[ds] = (floatx4){0.f,0.f,0.f,0.f};

        unsigned short pf[16];
        #pragma unroll
        for (int js = 0; js < 4; js++)
            #pragma unroll
            for (int r = 0; r < 4; r++)
                pf[js*4 + r] = *(const unsigned short*)&pb[((long)(w*16 + g4*4 + r)*512 + js*16 + ln)*8];

        for (int jt = 0; jt < 8; jt++) {
            __syncthreads();
            int j0 = jt*64;
            for (int c = t; c < 512; c += 256) {
                int r = c >> 3, c8 = c & 7;
                *(uint4*)((char*)sK + r*144 + c8*16) = *(const uint4*)(kb + (long)(j0 + r)*64 + c8*8);
            }
            for (int c = t; c < 512; c += 256) {
                int r = c >> 3, c8 = c & 7;
                *(uint4*)((char*)sV + r*144 + c8*16) = *(const uint4*)(vb + (long)r*512 + j0 + c8*8);
            }
            __syncthreads();

            unsigned short cur[16];
            #pragma unroll
            for (int e = 0; e < 16; e++) cur[e] = pf[e];
            if (jt < 7) {
                int jn = (jt + 1)*64;
                #pragma unroll
                for (int js = 0; js < 4; js++)
                    #pragma unroll
                    for (int r = 0; r < 4; r++)
                        pf[js*4 + r] = *(const unsigned short*)&pb[((long)(w*16 + g4*4 + r)*512 + jn + js*16 + ln)*8];
            }

            floatx4 sacc[4];
            #pragma unroll
            for (int js = 0; js < 4; js++) sacc[js] = (floatx4){0.f,0.f,0.f,0.f};
            #pragma unroll
            for (int kk = 0; kk < 2; kk++) {
                short8 aq = *(const short8*)((const char*)sQ + (w*16 + ln)*144 + kk*64 + g4*16);
                #pragma unroll
                for (int js = 0; js < 4; js++) {
                    short8 bk = *(const short8*)((const char*)sK + (js*16 + ln)*144 + kk*64 + g4*16);
                    sacc[js] = __builtin_amdgcn_mfma_f32_16x16x32_bf16(aq, bk, sacc[js], 0, 0, 0);
                }
            }
            #pragma unroll
            for (int js = 0; js < 4; js++)
                #pragma unroll
                for (int r = 0; r < 4; r++) {
                    float pv = bs2f((short)cur[js*4 + r]);
                    float e = exp2f((sacc[js][r]*0.125f + pv)*LOG2E);
                    lsum[r] += e;
                    sP[w][(g4*4 + r)*72 + js*16 + ln] = f2bs(e);
                }
            #pragma unroll
            for (int kk = 0; kk < 2; kk++) {
                short8 ap = *(const short8*)((const char*)sP[w] + ln*144 + kk*64 + g4*16);
                #pragma unroll
                for (int ds = 0; ds < 4; ds++) {
                    short8 bv = *(const short8*)((const char*)sV + (ds*16 + ln)*144 + kk*64 + g4*16);
                    oacc[ds] = __builtin_amdgcn_mfma_f32_16x16x32_bf16(ap, bv, oacc[ds], 0, 0, 0);
                }
            }
        }

        #pragma unroll
        for (int r = 0; r < 4; r++)
            #pragma unroll
            for (int m = 1; m < 16; m <<= 1) lsum[r] += __shfl_xor(lsum[r], m, 64);

        #pragma unroll
        for (int ds = 0; ds < 4; ds++)
            #pragma unroll
            for (int r = 0; r < 4; r++) {
                float val = oacc[ds][r] / lsum[r];
                int gi = i0 + w*16 + g4*4 + r;
                int col = h*64 + ds*16 + ln;
                heads[((long)b*SEQL + gi)*PROJ + col] = __float2bfloat16(val);
            }
        asm volatile("" ::: "memory");
    }
}

// ---------------- K4: fused tail (R5 structure), repeated ----------------
__global__ __launch_bounds__(256) void tail_kernel(
    const bf16* __restrict__ heads, const float* __restrict__ Wo,
    const float* __restrict__ seq, const float* __restrict__ g_att,
    const float* __restrict__ b_att, const float* __restrict__ W1,
    const float* __restrict__ b1, const float* __restrict__ W2,
    const float* __restrict__ b2, const float* __restrict__ g_ff,
    const float* __restrict__ b_ff, float* __restrict__ out)
{
    __shared__ __align__(16) short sH[8][520];
    __shared__ float sX[8][68];
    __shared__ float sHid[8][132];
    int t = threadIdx.x;
    int w = t >> 6, lane = t & 63;
    long g0 = (long)blockIdx.x*8;
    int r0 = w*2, r1 = w*2 + 1;

    #pragma unroll 1
    for (int rep = 0; rep < REP_TAIL; ++rep) {
        __syncthreads();
        for (int idx = t; idx < 512; idx += 256) {
            int r = idx >> 6, c8 = idx & 63;
            *(uint4*)((char*)&sH[r][0] + c8*16) = *(const uint4*)(heads + (g0 + r)*PROJ + c8*8);
        }
        __syncthreads();

        float acc0 = 0.f, acc1 = 0.f;
        #pragma unroll 4
        for (int kk8 = 0; kk8 < 64; kk8++) {
            short8 a0 = *(const short8*)&sH[r0][kk8*8];
            short8 a1 = *(const short8*)&sH[r1][kk8*8];
            #pragma unroll
            for (int e = 0; e < 8; e++) {
                float wv = Wo[(kk8*8 + e)*DEPTH + lane];
                acc0 += bs2f(a0[e])*wv;
                acc1 += bs2f(a1[e])*wv;
            }
        }
        float ga = g_att[lane], ba = b_att[lane];
        float xn[2];
        #pragma unroll
        for (int rr = 0; rr < 2; rr++) {
            long row = g0 + w*2 + rr;
            float x0 = (rr ? acc1 : acc0) + seq[row*DEPTH + lane];
            float s1 = x0, s2 = x0*x0;
            #pragma unroll
            for (int m = 1; m < 64; m <<= 1) { s1 += __shfl_xor(s1, m, 64); s2 += __shfl_xor(s2, m, 64); }
            float mu = s1*(1.f/64.f);
            float var = s2*(1.f/64.f) - mu*mu;
            float rstd = rsqrtf(var + 1e-5f);
            xn[rr] = (x0 - mu)*rstd*ga + ba;
            sX[w*2 + rr][lane] = xn[rr];
        }

        float b1a = b1[lane], b1b = b1[lane + 64];
        float h00 = b1a, h01 = b1b, h10 = b1a, h11 = b1b;
        #pragma unroll 4
        for (int kk = 0; kk < DEPTH; kk++) {
            float w0 = W1[kk*FFDIM + lane];
            float w1 = W1[kk*FFDIM + 64 + lane];
            float x0v = sX[r0][kk], x1v = sX[r1][kk];
            h00 += x0v*w0; h01 += x0v*w1;
            h10 += x1v*w0; h11 += x1v*w1;
        }
        sHid[r0][lane] = fmaxf(h00, 0.f); sHid[r0][lane + 64] = fmaxf(h01, 0.f);
        sHid[r1][lane] = fmaxf(h10, 0.f); sHid[r1][lane + 64] = fmaxf(h11, 0.f);

        float bb = b2[lane];
        float acc20 = bb, acc21 = bb;
        #pragma unroll 4
        for (int kk = 0; kk < FFDIM; kk++) {
            float wv = W2[kk*DEPTH + lane];
            acc20 += sHid[r0][kk]*wv;
            acc21 += sHid[r1][kk]*wv;
        }
        float gf = g_ff[lane], bf = b_ff[lane];
        #pragma unroll
        for (int rr = 0; rr < 2; rr++) {
            long row = g0 + w*2 + rr;
            float z = xn[rr] + (rr ? acc21 : acc20);
            float t1 = z, t2 = z*z;
            #pragma unroll
            for (int m = 1; m < 64; m <<= 1) { t1 += __shfl_xor(t1, m, 64); t2 += __shfl_xor(t2, m, 64); }
            float mu2 = t1*(1.f/64.f);
            float var2 = t2*(1.f/64.f) - mu2*mu2;
            float rstd2 = rsqrtf(var2 + 1e-5f);
            out[row*DEPTH + lane] = (z - mu2)*rstd2*gf + bf;
        }
        asm volatile("" ::: "memory");
    }
}

extern "C" void kernel_launch(void* const* d_in, const int* in_sizes, int n_in,
                              void* d_out, int out_size, void* d_ws, size_t ws_size,
                              hipStream_t stream) {
    const float* seq   = (const float*)d_in[0];
    const float* pos   = (const float*)d_in[1];
    const float* Wq    = (const float*)d_in[2];
    const float* Wk    = (const float*)d_in[3];
    const float* Wv    = (const float*)d_in[4];
    const float* Wo    = (const float*)d_in[5];
    const float* Wp    = (const float*)d_in[6];
    const float* bp    = (const float*)d_in[7];
    const float* W1    = (const float*)d_in[8];
    const float* b1    = (const float*)d_in[9];
    const float* W2    = (const float*)d_in[10];
    const float* b2    = (const float*)d_in[11];
    const float* g_att = (const float*)d_in[12];
    const float* b_att = (const float*)d_in[13];
    const float* g_ff  = (const float*)d_in[14];
    const float* b_ff  = (const float*)d_in[15];
    float* outp = (float*)d_out;

    bf16* qb  = (bf16*)d_ws;
    bf16* kb  = qb + 1048576;
    bf16* vTb = kb + 1048576;      // [B,h,d,S]
    bf16* pb  = vTb + 1048576;     // [B,S,S,h]
    bf16* hb  = pb + 8388608;

    qkv_kernel  <<<dim3(32, 4, 3), 256, 0, stream>>>(seq, Wq, Wk, Wv, qb, kb, vTb);
    pbias_kernel<<<8192,           256, 0, stream>>>(pos, Wp, bp, pb);
    attn_kernel <<<256,            256, 0, stream>>>(qb, kb, vTb, pb, hb);
    tail_kernel <<<256,            256, 0, stream>>>(hb, Wo, seq, g_att, b_att,
                                                     W1, b1, W2, b2, g_ff, b_ff, outp);
}

// Round 9
// 765.383 us; speedup vs baseline: 1.9421x; 1.9421x over previous
//
#include <hip/hip_runtime.h>
#include <hip/hip_bf16.h>

#define DEPTH 64
#define NH 8
#define SEQL 512
#define BATCH 4
#define FFDIM 128
#define PROJ (DEPTH*NH)   // 512
#define LOG2E 1.44269504088896340736f

// Diagnostic: pbias repeats its identical work 8x to claim the top rocprof
// row this round. Everything else runs once.
#define REP_PB 8

typedef __hip_bfloat16 bf16;
typedef __attribute__((ext_vector_type(8))) short short8;
typedef __attribute__((ext_vector_type(4))) float floatx4;

__device__ __forceinline__ short f2bs(float f) {
    __hip_bfloat16 h = __float2bfloat16(f);
    return *reinterpret_cast<short*>(&h);
}
__device__ __forceinline__ float bs2f(short s) {
    __hip_bfloat16 h = *reinterpret_cast<__hip_bfloat16*>(&s);
    return __bfloat162float(h);
}

// ---------------- K0: transpose+convert tail weights to bf16 ----------------
// WoT[64][512], W1T[128][64], W2T[64][128]  (all [col][k])
__global__ __launch_bounds__(256) void wconv_kernel(
    const float* __restrict__ Wo, const float* __restrict__ W1,
    const float* __restrict__ W2, bf16* __restrict__ WoT,
    bf16* __restrict__ W1T, bf16* __restrict__ W2T)
{
    int id = blockIdx.x*256 + threadIdx.x;      // 0..32767
    { int c = id >> 9, k = id & 511; WoT[id] = __float2bfloat16(Wo[k*64 + c]); }
    if (id < 8192) { int c = id >> 6, k = id & 63;  W1T[id] = __float2bfloat16(W1[k*128 + c]); }
    if (id < 8192) { int c = id >> 7, k = id & 127; W2T[id] = __float2bfloat16(W2[k*64 + c]); }
}

// ---------------- K1: QKV projection via MFMA, fp32 -> bf16 ----------------
__global__ __launch_bounds__(256) void qkv_kernel(
    const float* __restrict__ seq, const float* __restrict__ Wq,
    const float* __restrict__ Wk, const float* __restrict__ Wv,
    bf16* __restrict__ q, bf16* __restrict__ k, bf16* __restrict__ vT)
{
    __shared__ __align__(16) short sS[64][72];
    __shared__ __align__(16) short sW[128][72];
    __shared__ __align__(16) short sT[128][72];
    int t = threadIdx.x;
    int lane = t & 63, w = t >> 6;
    const float* W; int vflag = 0;
    bf16* out;
    if (blockIdx.z == 0)      { W = Wq; out = q; }
    else if (blockIdx.z == 1) { W = Wk; out = k; }
    else                      { W = Wv; out = vT; vflag = 1; }
    int m0 = blockIdx.x * 64;
    int n0 = blockIdx.y * 128;

    for (int idx = t; idx < 4096; idx += 256) {
        int r = idx >> 6, kk = idx & 63;
        sS[r][kk] = f2bs(seq[(long)(m0 + r)*64 + kk]);
    }
    for (int idx = t; idx < 8192; idx += 256) {
        int kk = idx >> 7, n = idx & 127;
        sW[n][kk] = f2bs(W[kk*512 + n0 + n]);
    }
    __syncthreads();

    int ln = lane & 15, g4 = lane >> 4;
    int mt = w;
    floatx4 acc[2][4];
    #pragma unroll
    for (int nh = 0; nh < 2; nh++)
        #pragma unroll
        for (int nt = 0; nt < 4; nt++) acc[nh][nt] = (floatx4){0.f,0.f,0.f,0.f};
    #pragma unroll
    for (int ks = 0; ks < 2; ks++) {
        short8 af = *(const short8*)&sS[mt*16 + ln][ks*32 + g4*8];
        #pragma unroll
        for (int nh = 0; nh < 2; nh++)
            #pragma unroll
            for (int nt = 0; nt < 4; nt++) {
                short8 bfv = *(const short8*)&sW[nh*64 + nt*16 + ln][ks*32 + g4*8];
                acc[nh][nt] = __builtin_amdgcn_mfma_f32_16x16x32_bf16(af, bfv, acc[nh][nt], 0, 0, 0);
            }
    }

    if (!vflag) {
        #pragma unroll
        for (int nh = 0; nh < 2; nh++)
            #pragma unroll
            for (int nt = 0; nt < 4; nt++)
                #pragma unroll
                for (int r = 0; r < 4; r++) {
                    int grow = m0 + mt*16 + g4*4 + r;
                    int col  = n0 + nh*64 + nt*16 + ln;
                    int b = grow >> 9, s = grow & 511;
                    int h = col >> 6, d = col & 63;
                    out[(((long)(b*8 + h)*512) + s)*64 + d] = __float2bfloat16(acc[nh][nt][r]);
                }
    } else {
        #pragma unroll
        for (int nh = 0; nh < 2; nh++)
            #pragma unroll
            for (int nt = 0; nt < 4; nt++)
                #pragma unroll
                for (int r = 0; r < 4; r++)
                    sT[nh*64 + nt*16 + ln][mt*16 + g4*4 + r] = f2bs(acc[nh][nt][r]);
        __syncthreads();
        int b = m0 >> 9, s0 = m0 & 511;
        for (int idx = t; idx < 1024; idx += 256) {
            int lc = idx >> 3, c8 = idx & 7;
            *(uint4*)(out + ((long)(b*512 + n0 + lc))*512 + s0 + c8*8) =
                *(const uint4*)&sT[lc][c8*8];
        }
    }
}

// ---------------- K2: positional bias (R5 structure), REP_PB reps ----------------
__global__ __launch_bounds__(256, 8) void pbias_kernel(
    const float* __restrict__ pos, const float* __restrict__ Wp,
    const float* __restrict__ bp, bf16* __restrict__ p)
{
    __shared__ __align__(16) float sW2[4][132];
    __shared__ float sb[8];
    int t = threadIdx.x;
    for (int i = t; i < 512; i += 256) {
        int sub = i >> 7, rest = i & 127;
        int lk = rest >> 3, h = rest & 7;
        int kk = ((lk >> 2) << 4) + sub*4 + (lk & 3);
        sW2[sub][lk*8 + h] = Wp[kk*8 + h];
    }
    if (t < 8) sb[t] = bp[t];
    __syncthreads();

    int sub = t & 3;
    int lr = t >> 2;
    long rowA = (long)blockIdx.x*128 + lr;
    long rowB = rowA + 64;

    #pragma unroll 1
    for (int rep = 0; rep < REP_PB; ++rep) {
        const float4* srcA = (const float4*)(pos + rowA*64);
        const float4* srcB = (const float4*)(pos + rowB*64);
        float4 chA[4], chB[4];
        #pragma unroll
        for (int i = 0; i < 4; i++) chA[i] = srcA[i*4 + sub];
        #pragma unroll
        for (int i = 0; i < 4; i++) chB[i] = srcB[i*4 + sub];

        float accA[8], accB[8];
        #pragma unroll
        for (int h = 0; h < 8; h++) { accA[h] = 0.f; accB[h] = 0.f; }
        #pragma unroll
        for (int i = 0; i < 4; i++) {
            #pragma unroll
            for (int e = 0; e < 4; e++) {
                int lk = i*4 + e;
                const float4* wr = (const float4*)&sW2[sub][lk*8];
                float4 wa = wr[0], wb = wr[1];
                float xA = ((const float*)&chA[i])[e];
                float xB = ((const float*)&chB[i])[e];
                accA[0] += xA*wa.x; accA[1] += xA*wa.y; accA[2] += xA*wa.z; accA[3] += xA*wa.w;
                accA[4] += xA*wb.x; accA[5] += xA*wb.y; accA[6] += xA*wb.z; accA[7] += xA*wb.w;
                accB[0] += xB*wa.x; accB[1] += xB*wa.y; accB[2] += xB*wa.z; accB[3] += xB*wa.w;
                accB[4] += xB*wb.x; accB[5] += xB*wb.y; accB[6] += xB*wb.z; accB[7] += xB*wb.w;
            }
        }
        #pragma unroll
        for (int h = 0; h < 8; h++) {
            accA[h] += __shfl_xor(accA[h], 1, 64);
            accA[h] += __shfl_xor(accA[h], 2, 64);
            accB[h] += __shfl_xor(accB[h], 1, 64);
            accB[h] += __shfl_xor(accB[h], 2, 64);
        }
        if (sub == 0) {
            short8 vA, vB;
            #pragma unroll
            for (int h = 0; h < 8; h++) {
                vA[h] = f2bs(accA[h] + sb[h]);
                vB[h] = f2bs(accB[h] + sb[h]);
            }
            *(short8*)(p + rowA*8) = vA;
            *(short8*)(p + rowB*8) = vB;
        }
        asm volatile("" ::: "memory");
    }
}

// ---------------- K3: flash attention (R5 structure, proven) ----------------
__global__ __launch_bounds__(256) void attn_kernel(
    const bf16* __restrict__ q, const bf16* __restrict__ k,
    const bf16* __restrict__ vT, const bf16* __restrict__ p,
    bf16* __restrict__ heads)
{
    __shared__ __align__(16) short sQ[64*72];
    __shared__ __align__(16) short sK[64*72];
    __shared__ __align__(16) short sV[64*72];
    __shared__ __align__(16) short sP[4][16*72];

    int t = threadIdx.x;
    int lane = t & 63, w = t >> 6;
    int bid = blockIdx.x;
    int it = bid & 7;
    int bh = bid >> 3;
    int i0 = it*64;
    int b = bh >> 3, h = bh & 7;

    const bf16* qb = q + ((long)bh*SEQL + i0)*DEPTH;
    const bf16* kb = k + (long)bh*SEQL*DEPTH;
    const bf16* vb = vT + (long)bh*DEPTH*SEQL;
    const bf16* pb = p + (((long)b*512 + i0)*512)*8 + h;

    for (int c = t; c < 512; c += 256) {
        int r = c >> 3, c8 = c & 7;
        *(uint4*)((char*)sQ + r*144 + c8*16) = *(const uint4*)(qb + r*64 + c8*8);
    }

    int ln = lane & 15, g4 = lane >> 4;
    float lsum[4];
    floatx4 oacc[4];
    #pragma unroll
    for (int r = 0; r < 4; r++) lsum[r] = 0.f;
    #pragma unroll
    for (int ds = 0; ds < 4; ds++) oacc[ds] = (floatx4){0.f,0.f,0.f,0.f};

    unsigned short pf[16];
    #pragma unroll
    for (int js = 0; js < 4; js++)
        #pragma unroll
        for (int r = 0; r < 4; r++)
            pf[js*4 + r] = *(const unsigned short*)&pb[((long)(w*16 + g4*4 + r)*512 + js*16 + ln)*8];

    for (int jt = 0; jt < 8; jt++) {
        __syncthreads();
        int j0 = jt*64;
        for (int c = t; c < 512; c += 256) {
            int r = c >> 3, c8 = c & 7;
            *(uint4*)((char*)sK + r*144 + c8*16) = *(const uint4*)(kb + (long)(j0 + r)*64 + c8*8);
        }
        for (int c = t; c < 512; c += 256) {
            int r = c >> 3, c8 = c & 7;
            *(uint4*)((char*)sV + r*144 + c8*16) = *(const uint4*)(vb + (long)r*512 + j0 + c8*8);
        }
        __syncthreads();

        unsigned short cur[16];
        #pragma unroll
        for (int e = 0; e < 16; e++) cur[e] = pf[e];
        if (jt < 7) {
            int jn = (jt + 1)*64;
            #pragma unroll
            for (int js = 0; js < 4; js++)
                #pragma unroll
                for (int r = 0; r < 4; r++)
                    pf[js*4 + r] = *(const unsigned short*)&pb[((long)(w*16 + g4*4 + r)*512 + jn + js*16 + ln)*8];
        }

        floatx4 sacc[4];
        #pragma unroll
        for (int js = 0; js < 4; js++) sacc[js] = (floatx4){0.f,0.f,0.f,0.f};
        #pragma unroll
        for (int kk = 0; kk < 2; kk++) {
            short8 aq = *(const short8*)((const char*)sQ + (w*16 + ln)*144 + kk*64 + g4*16);
            #pragma unroll
            for (int js = 0; js < 4; js++) {
                short8 bk = *(const short8*)((const char*)sK + (js*16 + ln)*144 + kk*64 + g4*16);
                sacc[js] = __builtin_amdgcn_mfma_f32_16x16x32_bf16(aq, bk, sacc[js], 0, 0, 0);
            }
        }
        #pragma unroll
        for (int js = 0; js < 4; js++)
            #pragma unroll
            for (int r = 0; r < 4; r++) {
                float pv = bs2f((short)cur[js*4 + r]);
                float e = exp2f((sacc[js][r]*0.125f + pv)*LOG2E);
                lsum[r] += e;
                sP[w][(g4*4 + r)*72 + js*16 + ln] = f2bs(e);
            }
        #pragma unroll
        for (int kk = 0; kk < 2; kk++) {
            short8 ap = *(const short8*)((const char*)sP[w] + ln*144 + kk*64 + g4*16);
            #pragma unroll
            for (int ds = 0; ds < 4; ds++) {
                short8 bv = *(const short8*)((const char*)sV + (ds*16 + ln)*144 + kk*64 + g4*16);
                oacc[ds] = __builtin_amdgcn_mfma_f32_16x16x32_bf16(ap, bv, oacc[ds], 0, 0, 0);
            }
        }
    }

    #pragma unroll
    for (int r = 0; r < 4; r++)
        #pragma unroll
        for (int m = 1; m < 16; m <<= 1) lsum[r] += __shfl_xor(lsum[r], m, 64);

    #pragma unroll
    for (int ds = 0; ds < 4; ds++)
        #pragma unroll
        for (int r = 0; r < 4; r++) {
            float val = oacc[ds][r] / lsum[r];
            int gi = i0 + w*16 + g4*4 + r;
            int col = h*64 + ds*16 + ln;
            heads[((long)b*SEQL + gi)*PROJ + col] = __float2bfloat16(val);
        }
}

// ---------------- K4: MFMA tail: o-proj + LN + FFN + LN ----------------
// 128 blocks x 256 thr (4 waves); 16 rows/block; waves split the N dim.
__global__ __launch_bounds__(256) void tail_kernel(
    const bf16* __restrict__ heads, const bf16* __restrict__ WoT,
    const float* __restrict__ seq, const float* __restrict__ g_att,
    const float* __restrict__ b_att, const bf16* __restrict__ W1T,
    const float* __restrict__ b1, const bf16* __restrict__ W2T,
    const float* __restrict__ b2, const float* __restrict__ g_ff,
    const float* __restrict__ b_ff, float* __restrict__ out)
{
    __shared__ __align__(16) short sH[16][520];
    __shared__ __align__(16) short sXn[16][72];
    __shared__ __align__(16) short sHid[16][136];
    __shared__ float fX[16][68];
    __shared__ float fZ[16][68];
    int t = threadIdx.x;
    int lane = t & 63, w = t >> 6;
    int ln = lane & 15, g4 = lane >> 4;
    long g0 = (long)blockIdx.x*16;

    // FIXED: full 16x512 tile = 1024 chunks of 8 shorts (was 512 -> half-staged)
    for (int idx = t; idx < 1024; idx += 256) {
        int r = idx >> 6, c16 = idx & 63;
        *(uint4*)&sH[r][c16*8] = *(const uint4*)(heads + (g0 + r)*512 + c16*8);
    }
    __syncthreads();

    // o-proj: wave w -> output cols w*16..w*16+15, K=512
    {
        floatx4 acc = (floatx4){0.f,0.f,0.f,0.f};
        const bf16* wo = WoT + ((long)(w*16 + ln))*512;
        #pragma unroll
        for (int ks = 0; ks < 16; ks++) {
            short8 a = *(const short8*)&sH[ln][ks*32 + g4*8];
            short8 b = *(const short8*)(wo + ks*32 + g4*8);
            acc = __builtin_amdgcn_mfma_f32_16x16x32_bf16(a, b, acc, 0, 0, 0);
        }
        #pragma unroll
        for (int r = 0; r < 4; r++) {
            int row = g4*4 + r, col = w*16 + ln;
            fX[row][col] = acc[r] + seq[(g0 + row)*64 + col];
        }
    }
    __syncthreads();

    // LN1: wave w handles rows w*4..w*4+3; 16 lanes/row, 4 cols/lane
    {
        int row = w*4 + (lane >> 4);
        int cg = lane & 15;
        float v[4]; float s1 = 0.f, s2 = 0.f;
        #pragma unroll
        for (int e = 0; e < 4; e++) { v[e] = fX[row][cg*4 + e]; s1 += v[e]; s2 += v[e]*v[e]; }
        #pragma unroll
        for (int m = 1; m < 16; m <<= 1) { s1 += __shfl_xor(s1, m, 64); s2 += __shfl_xor(s2, m, 64); }
        float mu = s1*(1.f/64.f);
        float var = s2*(1.f/64.f) - mu*mu;
        float rstd = rsqrtf(var + 1e-5f);
        #pragma unroll
        for (int e = 0; e < 4; e++) {
            int c = cg*4 + e;
            float xn = (v[e] - mu)*rstd*g_att[c] + b_att[c];
            fX[row][c] = xn;
            sXn[row][c] = f2bs(xn);
        }
    }
    __syncthreads();

    // FFN1: wave w -> cols w*32..w*32+31 (2 tiles), K=64; relu+bias
    #pragma unroll
    for (int nt = 0; nt < 2; nt++) {
        floatx4 a1 = (floatx4){0.f,0.f,0.f,0.f};
        int col = w*32 + nt*16 + ln;
        const bf16* w1p = W1T + (long)col*64;
        #pragma unroll
        for (int ks = 0; ks < 2; ks++) {
            short8 a = *(const short8*)&sXn[ln][ks*32 + g4*8];
            short8 b = *(const short8*)(w1p + ks*32 + g4*8);
            a1 = __builtin_amdgcn_mfma_f32_16x16x32_bf16(a, b, a1, 0, 0, 0);
        }
        float bias = b1[col];
        #pragma unroll
        for (int r = 0; r < 4; r++)
            sHid[g4*4 + r][col] = f2bs(fmaxf(a1[r] + bias, 0.f));
    }
    __syncthreads();

    // FFN2: wave w -> cols w*16..w*16+15, K=128; + b2 + residual xn
    {
        floatx4 a2 = (floatx4){0.f,0.f,0.f,0.f};
        int col = w*16 + ln;
        const bf16* w2p = W2T + (long)col*128;
        #pragma unroll
        for (int ks = 0; ks < 4; ks++) {
            short8 a = *(const short8*)&sHid[ln][ks*32 + g4*8];
            short8 b = *(const short8*)(w2p + ks*32 + g4*8);
            a2 = __builtin_amdgcn_mfma_f32_16x16x32_bf16(a, b, a2, 0, 0, 0);
        }
        float bias = b2[col];
        #pragma unroll
        for (int r = 0; r < 4; r++) {
            int row = g4*4 + r;
            fZ[row][col] = a2[r] + bias + fX[row][col];
        }
    }
    __syncthreads();

    // LN2 + coalesced float4 store
    {
        int row = w*4 + (lane >> 4);
        int cg = lane & 15;
        float v[4]; float s1 = 0.f, s2 = 0.f;
        #pragma unroll
        for (int e = 0; e < 4; e++) { v[e] = fZ[row][cg*4 + e]; s1 += v[e]; s2 += v[e]*v[e]; }
        #pragma unroll
        for (int m = 1; m < 16; m <<= 1) { s1 += __shfl_xor(s1, m, 64); s2 += __shfl_xor(s2, m, 64); }
        float mu = s1*(1.f/64.f);
        float var = s2*(1.f/64.f) - mu*mu;
        float rstd = rsqrtf(var + 1e-5f);
        float4 o;
        #pragma unroll
        for (int e = 0; e < 4; e++) {
            int c = cg*4 + e;
            ((float*)&o)[e] = (v[e] - mu)*rstd*g_ff[c] + b_ff[c];
        }
        *(float4*)(out + (g0 + row)*64 + cg*4) = o;
    }
}

extern "C" void kernel_launch(void* const* d_in, const int* in_sizes, int n_in,
                              void* d_out, int out_size, void* d_ws, size_t ws_size,
                              hipStream_t stream) {
    const float* seq   = (const float*)d_in[0];
    const float* pos   = (const float*)d_in[1];
    const float* Wq    = (const float*)d_in[2];
    const float* Wk    = (const float*)d_in[3];
    const float* Wv    = (const float*)d_in[4];
    const float* Wo    = (const float*)d_in[5];
    const float* Wp    = (const float*)d_in[6];
    const float* bp    = (const float*)d_in[7];
    const float* W1    = (const float*)d_in[8];
    const float* b1    = (const float*)d_in[9];
    const float* W2    = (const float*)d_in[10];
    const float* b2    = (const float*)d_in[11];
    const float* g_att = (const float*)d_in[12];
    const float* b_att = (const float*)d_in[13];
    const float* g_ff  = (const float*)d_in[14];
    const float* b_ff  = (const float*)d_in[15];
    float* outp = (float*)d_out;

    bf16* qb  = (bf16*)d_ws;
    bf16* kb  = qb + 1048576;
    bf16* vTb = kb + 1048576;      // [B,h,d,S]
    bf16* pb  = vTb + 1048576;     // [B,S,S,h]
    bf16* hb  = pb + 8388608;      // heads [B*S][512]
    bf16* WoT = hb + 1048576;      // [64][512]
    bf16* W1T = WoT + 32768;       // [128][64]
    bf16* W2T = W1T + 8192;        // [64][128]

    wconv_kernel<<<128,            256, 0, stream>>>(Wo, W1, W2, WoT, W1T, W2T);
    qkv_kernel  <<<dim3(32, 4, 3), 256, 0, stream>>>(seq, Wq, Wk, Wv, qb, kb, vTb);
    pbias_kernel<<<8192,           256, 0, stream>>>(pos, Wp, bp, pb);
    attn_kernel <<<256,            256, 0, stream>>>(qb, kb, vTb, pb, hb);
    tail_kernel <<<128,            256, 0, stream>>>(hb, WoT, seq, g_att, b_att,
                                                     W1T, b1, W2T, b2, g_ff, b_ff, outp);
}

// Round 10
// 101.159 us; speedup vs baseline: 14.6944x; 7.5661x over previous
//
#include <hip/hip_runtime.h>
#include <hip/hip_bf16.h>

#define DEPTH 64
#define NH 8
#define SEQL 512
#define BATCH 4
#define FFDIM 128
#define PROJ (DEPTH*NH)   // 512
#define LOG2E 1.44269504088896340736f

typedef __hip_bfloat16 bf16;
typedef __attribute__((ext_vector_type(8))) short short8;
typedef __attribute__((ext_vector_type(4))) float floatx4;

__device__ __forceinline__ short f2bs(float f) {
    __hip_bfloat16 h = __float2bfloat16(f);
    return *reinterpret_cast<short*>(&h);
}
__device__ __forceinline__ float bs2f(short s) {
    __hip_bfloat16 h = *reinterpret_cast<__hip_bfloat16*>(&s);
    return __bfloat162float(h);
}

// ---------------- K0: transpose+convert tail weights to bf16 ----------------
// WoT[64][512], W1T[128][64], W2T[64][128]  (all [col][k])
__global__ __launch_bounds__(256) void wconv_kernel(
    const float* __restrict__ Wo, const float* __restrict__ W1,
    const float* __restrict__ W2, bf16* __restrict__ WoT,
    bf16* __restrict__ W1T, bf16* __restrict__ W2T)
{
    int id = blockIdx.x*256 + threadIdx.x;      // 0..32767
    { int c = id >> 9, k = id & 511; WoT[id] = __float2bfloat16(Wo[k*64 + c]); }
    if (id < 8192) { int c = id >> 6, k = id & 63;  W1T[id] = __float2bfloat16(W1[k*128 + c]); }
    if (id < 8192) { int c = id >> 7, k = id & 127; W2T[id] = __float2bfloat16(W2[k*64 + c]); }
}

// ---------------- K1: QKV projection via MFMA, fp32 -> bf16 ----------------
__global__ __launch_bounds__(256) void qkv_kernel(
    const float* __restrict__ seq, const float* __restrict__ Wq,
    const float* __restrict__ Wk, const float* __restrict__ Wv,
    bf16* __restrict__ q, bf16* __restrict__ k, bf16* __restrict__ vT)
{
    __shared__ __align__(16) short sS[64][72];
    __shared__ __align__(16) short sW[128][72];
    __shared__ __align__(16) short sT[128][72];
    int t = threadIdx.x;
    int lane = t & 63, w = t >> 6;
    const float* W; int vflag = 0;
    bf16* out;
    if (blockIdx.z == 0)      { W = Wq; out = q; }
    else if (blockIdx.z == 1) { W = Wk; out = k; }
    else                      { W = Wv; out = vT; vflag = 1; }
    int m0 = blockIdx.x * 64;
    int n0 = blockIdx.y * 128;

    for (int idx = t; idx < 4096; idx += 256) {
        int r = idx >> 6, kk = idx & 63;
        sS[r][kk] = f2bs(seq[(long)(m0 + r)*64 + kk]);
    }
    for (int idx = t; idx < 8192; idx += 256) {
        int kk = idx >> 7, n = idx & 127;
        sW[n][kk] = f2bs(W[kk*512 + n0 + n]);
    }
    __syncthreads();

    int ln = lane & 15, g4 = lane >> 4;
    int mt = w;
    floatx4 acc[2][4];
    #pragma unroll
    for (int nh = 0; nh < 2; nh++)
        #pragma unroll
        for (int nt = 0; nt < 4; nt++) acc[nh][nt] = (floatx4){0.f,0.f,0.f,0.f};
    #pragma unroll
    for (int ks = 0; ks < 2; ks++) {
        short8 af = *(const short8*)&sS[mt*16 + ln][ks*32 + g4*8];
        #pragma unroll
        for (int nh = 0; nh < 2; nh++)
            #pragma unroll
            for (int nt = 0; nt < 4; nt++) {
                short8 bfv = *(const short8*)&sW[nh*64 + nt*16 + ln][ks*32 + g4*8];
                acc[nh][nt] = __builtin_amdgcn_mfma_f32_16x16x32_bf16(af, bfv, acc[nh][nt], 0, 0, 0);
            }
    }

    if (!vflag) {
        #pragma unroll
        for (int nh = 0; nh < 2; nh++)
            #pragma unroll
            for (int nt = 0; nt < 4; nt++)
                #pragma unroll
                for (int r = 0; r < 4; r++) {
                    int grow = m0 + mt*16 + g4*4 + r;
                    int col  = n0 + nh*64 + nt*16 + ln;
                    int b = grow >> 9, s = grow & 511;
                    int h = col >> 6, d = col & 63;
                    out[(((long)(b*8 + h)*512) + s)*64 + d] = __float2bfloat16(acc[nh][nt][r]);
                }
    } else {
        #pragma unroll
        for (int nh = 0; nh < 2; nh++)
            #pragma unroll
            for (int nt = 0; nt < 4; nt++)
                #pragma unroll
                for (int r = 0; r < 4; r++)
                    sT[nh*64 + nt*16 + ln][mt*16 + g4*4 + r] = f2bs(acc[nh][nt][r]);
        __syncthreads();
        int b = m0 >> 9, s0 = m0 & 511;
        for (int idx = t; idx < 1024; idx += 256) {
            int lc = idx >> 3, c8 = idx & 7;
            *(uint4*)(out + ((long)(b*512 + n0 + lc))*512 + s0 + c8*8) =
                *(const uint4*)&sT[lc][c8*8];
        }
    }
}

// ---------------- K2: positional bias — LDS-staged full-line writes ----------------
// Reads unchanged (R5: instr = 16 rows x 64B full lines, FETCH measured ~ideal).
// FIX: results staged in LDS, then 128 threads store 16B each = two dense 1KB
// bursts (all-lane, full-line) instead of 16-of-64-lane masked stores that
// caused 5x write amplification via read-modify-write (R9 counters).
__global__ __launch_bounds__(256, 8) void pbias_kernel(
    const float* __restrict__ pos, const float* __restrict__ Wp,
    const float* __restrict__ bp, bf16* __restrict__ p)
{
    __shared__ __align__(16) float sW2[4][132];
    __shared__ float sb[8];
    __shared__ __align__(16) short sOut[128][8];   // 2KB output stage
    int t = threadIdx.x;
    for (int i = t; i < 512; i += 256) {
        int sub = i >> 7, rest = i & 127;
        int lk = rest >> 3, h = rest & 7;
        int kk = ((lk >> 2) << 4) + sub*4 + (lk & 3);
        sW2[sub][lk*8 + h] = Wp[kk*8 + h];
    }
    if (t < 8) sb[t] = bp[t];
    __syncthreads();

    int sub = t & 3;
    int lr = t >> 2;                            // 0..63
    long rowA = (long)blockIdx.x*128 + lr;
    long rowB = rowA + 64;

    const float4* srcA = (const float4*)(pos + rowA*64);
    const float4* srcB = (const float4*)(pos + rowB*64);
    float4 chA[4], chB[4];
    #pragma unroll
    for (int i = 0; i < 4; i++) chA[i] = srcA[i*4 + sub];
    #pragma unroll
    for (int i = 0; i < 4; i++) chB[i] = srcB[i*4 + sub];

    float accA[8], accB[8];
    #pragma unroll
    for (int h = 0; h < 8; h++) { accA[h] = 0.f; accB[h] = 0.f; }
    #pragma unroll
    for (int i = 0; i < 4; i++) {
        #pragma unroll
        for (int e = 0; e < 4; e++) {
            int lk = i*4 + e;
            const float4* wr = (const float4*)&sW2[sub][lk*8];
            float4 wa = wr[0], wb = wr[1];
            float xA = ((const float*)&chA[i])[e];
            float xB = ((const float*)&chB[i])[e];
            accA[0] += xA*wa.x; accA[1] += xA*wa.y; accA[2] += xA*wa.z; accA[3] += xA*wa.w;
            accA[4] += xA*wb.x; accA[5] += xA*wb.y; accA[6] += xA*wb.z; accA[7] += xA*wb.w;
            accB[0] += xB*wa.x; accB[1] += xB*wa.y; accB[2] += xB*wa.z; accB[3] += xB*wa.w;
            accB[4] += xB*wb.x; accB[5] += xB*wb.y; accB[6] += xB*wb.z; accB[7] += xB*wb.w;
        }
    }
    #pragma unroll
    for (int h = 0; h < 8; h++) {
        accA[h] += __shfl_xor(accA[h], 1, 64);
        accA[h] += __shfl_xor(accA[h], 2, 64);
        accB[h] += __shfl_xor(accB[h], 1, 64);
        accB[h] += __shfl_xor(accB[h], 2, 64);
    }
    if (sub == 0) {
        short8 vA, vB;
        #pragma unroll
        for (int h = 0; h < 8; h++) {
            vA[h] = f2bs(accA[h] + sb[h]);
            vB[h] = f2bs(accB[h] + sb[h]);
        }
        *(short8*)&sOut[lr][0]      = vA;
        *(short8*)&sOut[64 + lr][0] = vB;
    }
    __syncthreads();
    if (t < 128)
        *(uint4*)(p + ((long)blockIdx.x*128 + t)*8) = *(const uint4*)&sOut[t][0];
}

// ---------------- K3: flash attention (R5 structure, proven) ----------------
__global__ __launch_bounds__(256) void attn_kernel(
    const bf16* __restrict__ q, const bf16* __restrict__ k,
    const bf16* __restrict__ vT, const bf16* __restrict__ p,
    bf16* __restrict__ heads)
{
    __shared__ __align__(16) short sQ[64*72];
    __shared__ __align__(16) short sK[64*72];
    __shared__ __align__(16) short sV[64*72];
    __shared__ __align__(16) short sP[4][16*72];

    int t = threadIdx.x;
    int lane = t & 63, w = t >> 6;
    int bid = blockIdx.x;
    int it = bid & 7;
    int bh = bid >> 3;
    int i0 = it*64;
    int b = bh >> 3, h = bh & 7;

    const bf16* qb = q + ((long)bh*SEQL + i0)*DEPTH;
    const bf16* kb = k + (long)bh*SEQL*DEPTH;
    const bf16* vb = vT + (long)bh*DEPTH*SEQL;
    const bf16* pb = p + (((long)b*512 + i0)*512)*8 + h;

    for (int c = t; c < 512; c += 256) {
        int r = c >> 3, c8 = c & 7;
        *(uint4*)((char*)sQ + r*144 + c8*16) = *(const uint4*)(qb + r*64 + c8*8);
    }

    int ln = lane & 15, g4 = lane >> 4;
    float lsum[4];
    floatx4 oacc[4];
    #pragma unroll
    for (int r = 0; r < 4; r++) lsum[r] = 0.f;
    #pragma unroll
    for (int ds = 0; ds < 4; ds++) oacc[ds] = (floatx4){0.f,0.f,0.f,0.f};

    unsigned short pf[16];
    #pragma unroll
    for (int js = 0; js < 4; js++)
        #pragma unroll
        for (int r = 0; r < 4; r++)
            pf[js*4 + r] = *(const unsigned short*)&pb[((long)(w*16 + g4*4 + r)*512 + js*16 + ln)*8];

    for (int jt = 0; jt < 8; jt++) {
        __syncthreads();
        int j0 = jt*64;
        for (int c = t; c < 512; c += 256) {
            int r = c >> 3, c8 = c & 7;
            *(uint4*)((char*)sK + r*144 + c8*16) = *(const uint4*)(kb + (long)(j0 + r)*64 + c8*8);
        }
        for (int c = t; c < 512; c += 256) {
            int r = c >> 3, c8 = c & 7;
            *(uint4*)((char*)sV + r*144 + c8*16) = *(const uint4*)(vb + (long)r*512 + j0 + c8*8);
        }
        __syncthreads();

        unsigned short cur[16];
        #pragma unroll
        for (int e = 0; e < 16; e++) cur[e] = pf[e];
        if (jt < 7) {
            int jn = (jt + 1)*64;
            #pragma unroll
            for (int js = 0; js < 4; js++)
                #pragma unroll
                for (int r = 0; r < 4; r++)
                    pf[js*4 + r] = *(const unsigned short*)&pb[((long)(w*16 + g4*4 + r)*512 + jn + js*16 + ln)*8];
        }

        floatx4 sacc[4];
        #pragma unroll
        for (int js = 0; js < 4; js++) sacc[js] = (floatx4){0.f,0.f,0.f,0.f};
        #pragma unroll
        for (int kk = 0; kk < 2; kk++) {
            short8 aq = *(const short8*)((const char*)sQ + (w*16 + ln)*144 + kk*64 + g4*16);
            #pragma unroll
            for (int js = 0; js < 4; js++) {
                short8 bk = *(const short8*)((const char*)sK + (js*16 + ln)*144 + kk*64 + g4*16);
                sacc[js] = __builtin_amdgcn_mfma_f32_16x16x32_bf16(aq, bk, sacc[js], 0, 0, 0);
            }
        }
        #pragma unroll
        for (int js = 0; js < 4; js++)
            #pragma unroll
            for (int r = 0; r < 4; r++) {
                float pv = bs2f((short)cur[js*4 + r]);
                float e = exp2f((sacc[js][r]*0.125f + pv)*LOG2E);
                lsum[r] += e;
                sP[w][(g4*4 + r)*72 + js*16 + ln] = f2bs(e);
            }
        #pragma unroll
        for (int kk = 0; kk < 2; kk++) {
            short8 ap = *(const short8*)((const char*)sP[w] + ln*144 + kk*64 + g4*16);
            #pragma unroll
            for (int ds = 0; ds < 4; ds++) {
                short8 bv = *(const short8*)((const char*)sV + (ds*16 + ln)*144 + kk*64 + g4*16);
                oacc[ds] = __builtin_amdgcn_mfma_f32_16x16x32_bf16(ap, bv, oacc[ds], 0, 0, 0);
            }
        }
    }

    #pragma unroll
    for (int r = 0; r < 4; r++)
        #pragma unroll
        for (int m = 1; m < 16; m <<= 1) lsum[r] += __shfl_xor(lsum[r], m, 64);

    #pragma unroll
    for (int ds = 0; ds < 4; ds++)
        #pragma unroll
        for (int r = 0; r < 4; r++) {
            float val = oacc[ds][r] / lsum[r];
            int gi = i0 + w*16 + g4*4 + r;
            int col = h*64 + ds*16 + ln;
            heads[((long)b*SEQL + gi)*PROJ + col] = __float2bfloat16(val);
        }
}

// ---------------- K4: MFMA tail: o-proj + LN + FFN + LN ----------------
// 128 blocks x 256 thr (4 waves); 16 rows/block; waves split the N dim.
__global__ __launch_bounds__(256) void tail_kernel(
    const bf16* __restrict__ heads, const bf16* __restrict__ WoT,
    const float* __restrict__ seq, const float* __restrict__ g_att,
    const float* __restrict__ b_att, const bf16* __restrict__ W1T,
    const float* __restrict__ b1, const bf16* __restrict__ W2T,
    const float* __restrict__ b2, const float* __restrict__ g_ff,
    const float* __restrict__ b_ff, float* __restrict__ out)
{
    __shared__ __align__(16) short sH[16][520];
    __shared__ __align__(16) short sXn[16][72];
    __shared__ __align__(16) short sHid[16][136];
    __shared__ float fX[16][68];
    __shared__ float fZ[16][68];
    int t = threadIdx.x;
    int lane = t & 63, w = t >> 6;
    int ln = lane & 15, g4 = lane >> 4;
    long g0 = (long)blockIdx.x*16;

    for (int idx = t; idx < 1024; idx += 256) {
        int r = idx >> 6, c16 = idx & 63;
        *(uint4*)&sH[r][c16*8] = *(const uint4*)(heads + (g0 + r)*512 + c16*8);
    }
    __syncthreads();

    // o-proj: wave w -> output cols w*16..w*16+15, K=512
    {
        floatx4 acc = (floatx4){0.f,0.f,0.f,0.f};
        const bf16* wo = WoT + ((long)(w*16 + ln))*512;
        #pragma unroll
        for (int ks = 0; ks < 16; ks++) {
            short8 a = *(const short8*)&sH[ln][ks*32 + g4*8];
            short8 b = *(const short8*)(wo + ks*32 + g4*8);
            acc = __builtin_amdgcn_mfma_f32_16x16x32_bf16(a, b, acc, 0, 0, 0);
        }
        #pragma unroll
        for (int r = 0; r < 4; r++) {
            int row = g4*4 + r, col = w*16 + ln;
            fX[row][col] = acc[r] + seq[(g0 + row)*64 + col];
        }
    }
    __syncthreads();

    // LN1
    {
        int row = w*4 + (lane >> 4);
        int cg = lane & 15;
        float v[4]; float s1 = 0.f, s2 = 0.f;
        #pragma unroll
        for (int e = 0; e < 4; e++) { v[e] = fX[row][cg*4 + e]; s1 += v[e]; s2 += v[e]*v[e]; }
        #pragma unroll
        for (int m = 1; m < 16; m <<= 1) { s1 += __shfl_xor(s1, m, 64); s2 += __shfl_xor(s2, m, 64); }
        float mu = s1*(1.f/64.f);
        float var = s2*(1.f/64.f) - mu*mu;
        float rstd = rsqrtf(var + 1e-5f);
        #pragma unroll
        for (int e = 0; e < 4; e++) {
            int c = cg*4 + e;
            float xn = (v[e] - mu)*rstd*g_att[c] + b_att[c];
            fX[row][c] = xn;
            sXn[row][c] = f2bs(xn);
        }
    }
    __syncthreads();

    // FFN1: wave w -> cols w*32..w*32+31, K=64; relu+bias
    #pragma unroll
    for (int nt = 0; nt < 2; nt++) {
        floatx4 a1 = (floatx4){0.f,0.f,0.f,0.f};
        int col = w*32 + nt*16 + ln;
        const bf16* w1p = W1T + (long)col*64;
        #pragma unroll
        for (int ks = 0; ks < 2; ks++) {
            short8 a = *(const short8*)&sXn[ln][ks*32 + g4*8];
            short8 b = *(const short8*)(w1p + ks*32 + g4*8);
            a1 = __builtin_amdgcn_mfma_f32_16x16x32_bf16(a, b, a1, 0, 0, 0);
        }
        float bias = b1[col];
        #pragma unroll
        for (int r = 0; r < 4; r++)
            sHid[g4*4 + r][col] = f2bs(fmaxf(a1[r] + bias, 0.f));
    }
    __syncthreads();

    // FFN2: wave w -> cols w*16..w*16+15, K=128; + b2 + residual xn
    {
        floatx4 a2 = (floatx4){0.f,0.f,0.f,0.f};
        int col = w*16 + ln;
        const bf16* w2p = W2T + (long)col*128;
        #pragma unroll
        for (int ks = 0; ks < 4; ks++) {
            short8 a = *(const short8*)&sHid[ln][ks*32 + g4*8];
            short8 b = *(const short8*)(w2p + ks*32 + g4*8);
            a2 = __builtin_amdgcn_mfma_f32_16x16x32_bf16(a, b, a2, 0, 0, 0);
        }
        float bias = b2[col];
        #pragma unroll
        for (int r = 0; r < 4; r++) {
            int row = g4*4 + r;
            fZ[row][col] = a2[r] + bias + fX[row][col];
        }
    }
    __syncthreads();

    // LN2 + coalesced float4 store
    {
        int row = w*4 + (lane >> 4);
        int cg = lane & 15;
        float v[4]; float s1 = 0.f, s2 = 0.f;
        #pragma unroll
        for (int e = 0; e < 4; e++) { v[e] = fZ[row][cg*4 + e]; s1 += v[e]; s2 += v[e]*v[e]; }
        #pragma unroll
        for (int m = 1; m < 16; m <<= 1) { s1 += __shfl_xor(s1, m, 64); s2 += __shfl_xor(s2, m, 64); }
        float mu = s1*(1.f/64.f);
        float var = s2*(1.f/64.f) - mu*mu;
        float rstd = rsqrtf(var + 1e-5f);
        float4 o;
        #pragma unroll
        for (int e = 0; e < 4; e++) {
            int c = cg*4 + e;
            ((float*)&o)[e] = (v[e] - mu)*rstd*g_ff[c] + b_ff[c];
        }
        *(float4*)(out + (g0 + row)*64 + cg*4) = o;
    }
}

extern "C" void kernel_launch(void* const* d_in, const int* in_sizes, int n_in,
                              void* d_out, int out_size, void* d_ws, size_t ws_size,
                              hipStream_t stream) {
    const float* seq   = (const float*)d_in[0];
    const float* pos   = (const float*)d_in[1];
    const float* Wq    = (const float*)d_in[2];
    const float* Wk    = (const float*)d_in[3];
    const float* Wv    = (const float*)d_in[4];
    const float* Wo    = (const float*)d_in[5];
    const float* Wp    = (const float*)d_in[6];
    const float* bp    = (const float*)d_in[7];
    const float* W1    = (const float*)d_in[8];
    const float* b1    = (const float*)d_in[9];
    const float* W2    = (const float*)d_in[10];
    const float* b2    = (const float*)d_in[11];
    const float* g_att = (const float*)d_in[12];
    const float* b_att = (const float*)d_in[13];
    const float* g_ff  = (const float*)d_in[14];
    const float* b_ff  = (const float*)d_in[15];
    float* outp = (float*)d_out;

    bf16* qb  = (bf16*)d_ws;
    bf16* kb  = qb + 1048576;
    bf16* vTb = kb + 1048576;      // [B,h,d,S]
    bf16* pb  = vTb + 1048576;     // [B,S,S,h]
    bf16* hb  = pb + 8388608;      // heads [B*S][512]
    bf16* WoT = hb + 1048576;      // [64][512]
    bf16* W1T = WoT + 32768;       // [128][64]
    bf16* W2T = W1T + 8192;        // [64][128]

    wconv_kernel<<<128,            256, 0, stream>>>(Wo, W1, W2, WoT, W1T, W2T);
    qkv_kernel  <<<dim3(32, 4, 3), 256, 0, stream>>>(seq, Wq, Wk, Wv, qb, kb, vTb);
    pbias_kernel<<<8192,           256, 0, stream>>>(pos, Wp, bp, pb);
    attn_kernel <<<256,            256, 0, stream>>>(qb, kb, vTb, pb, hb);
    tail_kernel <<<128,            256, 0, stream>>>(hb, WoT, seq, g_att, b_att,
                                                     W1T, b1, W2T, b2, g_ff, b_ff, outp);
}